// Round 9
// baseline (148.056 us; speedup 1.0000x reference)
//
#include <hip/hip_runtime.h>
#include <math.h>

#define B 16
#define N 200
#define HID 64
#define NH 2
#define D 32
#define EPSF 1e-12f

// 1/sqrt(32)
#define RSQRT_D 0.17677669529663687f

// ---------------- Kernel 1: projections + folded pos + order/dist scalars ----
__global__ __launch_bounds__(256) void k_proj(
    const float* __restrict__ x,
    const float* __restrict__ pk,
    const float* __restrict__ pv,
    const float* __restrict__ Wq, const float* __restrict__ bq,
    const float* __restrict__ Wk, const float* __restrict__ bk,
    const float* __restrict__ Wv, const float* __restrict__ bv,
    const float* __restrict__ order_w, const float* __restrict__ dist_w,
    float* __restrict__ q,
    float* __restrict__ kp,
    float* __restrict__ vp,
    float* __restrict__ qo, float* __restrict__ ko,
    float* __restrict__ qd, float* __restrict__ kd)
{
    __shared__ float sX[4][HID];
    const int tid = threadIdx.x;
    const int sub = tid >> 6;
    const int o   = tid & 63;
    const int row = blockIdx.x * 4 + sub;

    sX[sub][o] = x[row * HID + o];
    __syncthreads();

    float qv = bq[o], kv = bk[o], vv = bv[o];
    #pragma unroll 8
    for (int c = 0; c < HID; ++c) {
        const float xv = sX[sub][c];
        qv = fmaf(xv, Wq[o * HID + c], qv);
        kv = fmaf(xv, Wk[o * HID + c], kv);
        vv = fmaf(xv, Wv[o * HID + c], vv);
    }
    q [row * HID + o] = qv;
    kp[row * HID + o] = kv + pk[row * HID + o];
    vp[row * HID + o] = vv + pv[row * HID + o];

    const int d = o & 31;
    float qov = qv * order_w[d];
    float kov = kv * order_w[D + d];
    float qdv = qv * dist_w[d];
    float kdv = kv * dist_w[D + d];
    #pragma unroll
    for (int m = 16; m >= 1; m >>= 1) {
        qov += __shfl_xor(qov, m);
        kov += __shfl_xor(kov, m);
        qdv += __shfl_xor(qdv, m);
        kdv += __shfl_xor(kdv, m);
    }
    if (d == 0) {
        const int bb = row / N;
        const int ii = row - bb * N;
        const int h  = o >> 5;
        const int idx = (bb * NH + h) * N + ii;
        qo[idx] = qov;  ko[idx] = kov;
        qd[idx] = qdv;  kd[idx] = kdv;
    }
}

// ---------------- Kernel 2: S_pre[b,h,i,j] = (q.kp + order + dist)/sqrtD + mask
__global__ __launch_bounds__(256) void k_pre(
    const float* __restrict__ q, const float* __restrict__ kp,
    const float* __restrict__ amask,
    const float* __restrict__ qo, const float* __restrict__ ko,
    const float* __restrict__ qd, const float* __restrict__ kd,
    const float* __restrict__ order_b, const float* __restrict__ dist_b,
    const float* __restrict__ scalar,
    float* __restrict__ S_pre)        // [B*NH*N, N]
{
    __shared__ float sQ[25][33];
    __shared__ float sK[200][33];
    __shared__ float sGd[200];
    __shared__ float sQo[25], sQd[25];
    __shared__ float sKo[200], sKd[200];

    const int tid = threadIdx.x;
    const int bid = blockIdx.x;
    const int it  = bid & 7;          // i-tile
    const int bh  = bid >> 3;
    const int b   = bh >> 1;
    const int h   = bh & 1;
    const int i0  = it * 25;

    for (int e = tid; e < 200 * 32; e += 256) {
        const int j = e >> 5, d = e & 31;
        sK[j][d] = kp[((size_t)b * N + j) * HID + h * D + d];
    }
    for (int e = tid; e < 25 * 32; e += 256) {
        const int ii = e >> 5, d = e & 31;
        sQ[ii][d] = q[((size_t)b * N + i0 + ii) * HID + h * D + d];
    }
    for (int e = tid; e < 200; e += 256) {
        sGd[e] = logf((float)e + 1.0f);
        sKo[e] = ko[(size_t)bh * N + e];
        sKd[e] = kd[(size_t)bh * N + e];
    }
    if (tid < 25) {
        sQo[tid] = qo[(size_t)bh * N + i0 + tid];
        sQd[tid] = qd[(size_t)bh * N + i0 + tid];
    }
    const float ob = order_b[0];
    const float db = dist_b[0];
    const float sc = scalar[0];
    const float sc2h = 0.5f * sc * sc;
    __syncthreads();

    for (int e = tid; e < 25 * 200; e += 256) {
        const int ii = e / 200;
        const int jj = e - ii * 200;
        const int i  = i0 + ii;
        float dot = 0.0f;
        #pragma unroll
        for (int d = 0; d < 32; ++d)
            dot = fmaf(sQ[ii][d], sK[jj][d], dot);
        const float lo = sQo[ii] + sKo[jj] + ob;
        const float xs = (jj > i) ? -lo : lo;
        const float eo = -log1pf(expf(xs));
        const float pd = sQd[ii] + sKd[jj] + db;
        const int   ad = (jj > i) ? (jj - i) : (i - jj);
        const float dv = sGd[ad] - pd;
        const float ed = -sc2h * dv * dv;
        S_pre[((size_t)bh * N + i) * N + jj] =
            (dot + eo + ed) * RSQRT_D + amask[((size_t)b * N + i) * N + jj];
    }
}

// ---------------- Kernel 3: DMA-staged tk/tv; softmax; P; ctx_tv ------------
// One 256-thread block per (b,i). tk (200x64 f32 = 51.2KB) staged to LDS via
// global_load_lds (50 x 1KB wave-calls, 12-13 in flight per wave), then
// consumed from LDS. tv staging overlaps softmax. XOR-swizzle (pre-swizzled
// GLOBAL source + swizzled LDS read; linear DMA dest) kills the stride-256
// bank conflict.
__global__ __launch_bounds__(256) void k_attn(
    const float* __restrict__ q,
    const float* __restrict__ tk,     // [B,N,N,HID]
    const float* __restrict__ tv,
    const float* __restrict__ S_pre,  // [B*NH*N, N]
    float* __restrict__ P,            // [B*NH*N, N]
    float* __restrict__ ctx_tv)       // [B*N, HID]
{
    __shared__ float smem[12800 + 416];   // 51.2KB row buffer + S_dot/SP[2][208]
    float* S_dot = smem + 12800;

    const int tid  = threadIdx.x;
    const int w    = tid >> 6;        // wave 0..3
    const int lane = tid & 63;
    const int g    = lane >> 4;       // row-in-quad 0..3
    const int c    = lane & 15;       // float4 col 0..15 (head = c>>3)
    const int hd   = c >> 3;
    const int bi   = blockIdx.x;      // b*N + i
    const int b    = bi / N;
    const int i    = bi - b * N;

    float4 qf = ((const float4*)(q + (size_t)bi * HID))[c];
    qf.x *= RSQRT_D; qf.y *= RSQRT_D; qf.z *= RSQRT_D; qf.w *= RSQRT_D;

    const float* tkB = tk + (size_t)bi * N * HID;
    const float* tvB = tv + (size_t)bi * N * HID;

    // ---- stage tk: 50 x 1KB DMA calls (idx = w + 4r), linear LDS dest,
    //      pre-swizzled global source ----
#define STAGE(SRC)                                                            \
    for (int r = 0; r < 13; ++r) {                                            \
        const int idx = w + 4 * r;                                            \
        if (idx < 50) {                                                       \
            const int row  = idx * 4 + (lane >> 4);                           \
            const int colf = ((lane & 15) << 2) ^ ((row & 7) << 2);           \
            const float* gp = (SRC) + row * 64 + colf;                        \
            float* lp = smem + idx * 256;  /* wave-uniform */                 \
            __builtin_amdgcn_global_load_lds(                                 \
                (const __attribute__((address_space(1))) void*)gp,            \
                (__attribute__((address_space(3))) void*)lp, 16, 0, 0);       \
        }                                                                     \
    }

    STAGE(tkB)
    asm volatile("s_waitcnt vmcnt(0)" ::: "memory");
    __syncthreads();

    // ---- dots from LDS (swizzled read) ----
    #pragma unroll
    for (int itr = 0; itr < 13; ++itr) {
        if (itr == 12 && w >= 2) break;
        const int j = itr * 16 + w * 4 + g;
        const int colf = (c << 2) ^ ((j & 7) << 2);
        const float4 f = *(const float4*)(smem + j * 64 + colf);
        float part = qf.x * f.x + qf.y * f.y + qf.z * f.z + qf.w * f.w;
        part += __shfl_xor(part, 1);
        part += __shfl_xor(part, 2);
        part += __shfl_xor(part, 4);
        if ((c & 7) == 0) S_dot[hd * 208 + j] = part;
    }
    __syncthreads();   // S_dot complete; tk buffer free

    // ---- stage tv (DMA overlaps softmax) ----
    STAGE(tvB)

    // ---- softmax: wave w<2 handles head w ----
    if (w < 2) {
        const float* spr = S_pre + ((size_t)(2 * b + w) * N + i) * N;
        float* sd = S_dot + w * 208;
        const float s0 = spr[lane]       + sd[lane];
        const float s1 = spr[lane + 64]  + sd[lane + 64];
        const float s2 = spr[lane + 128] + sd[lane + 128];
        const float s3 = (lane < 8) ? (spr[lane + 192] + sd[lane + 192]) : -INFINITY;
        float m = fmaxf(fmaxf(s0, s1), fmaxf(s2, s3));
        #pragma unroll
        for (int k = 32; k >= 1; k >>= 1) m = fmaxf(m, __shfl_xor(m, k));
        const float e0 = expf(s0 - m);
        const float e1 = expf(s1 - m);
        const float e2 = expf(s2 - m);
        const float e3 = (lane < 8) ? expf(s3 - m) : 0.0f;
        float t = e0 + e1 + e2 + e3;
        #pragma unroll
        for (int k = 32; k >= 1; k >>= 1) t += __shfl_xor(t, k);
        const float rinv = 1.0f / t;
        float* prow = P + ((size_t)(2 * b + w) * N + i) * N;
        sd[lane]       = e0 * rinv;  prow[lane]       = e0 * rinv;
        sd[lane + 64]  = e1 * rinv;  prow[lane + 64]  = e1 * rinv;
        sd[lane + 128] = e2 * rinv;  prow[lane + 128] = e2 * rinv;
        if (lane < 8) { sd[lane + 192] = e3 * rinv;  prow[lane + 192] = e3 * rinv; }
    }
    asm volatile("s_waitcnt vmcnt(0)" ::: "memory");
    __syncthreads();   // tv staged + probs ready

    // ---- ctx_tv = sum_j p_j * tv[i,j] ----
    float4 acc = make_float4(0.f, 0.f, 0.f, 0.f);
    #pragma unroll
    for (int itr = 0; itr < 13; ++itr) {
        if (itr == 12 && w >= 2) break;
        const int j = itr * 16 + w * 4 + g;
        const int colf = (c << 2) ^ ((j & 7) << 2);
        const float4 f = *(const float4*)(smem + j * 64 + colf);
        const float pj = S_dot[hd * 208 + j];
        acc.x = fmaf(pj, f.x, acc.x);
        acc.y = fmaf(pj, f.y, acc.y);
        acc.z = fmaf(pj, f.z, acc.z);
        acc.w = fmaf(pj, f.w, acc.w);
    }
    // reduce over g (4 rows-in-quad)
    #pragma unroll
    for (int k = 16; k <= 32; k <<= 1) {
        acc.x += __shfl_xor(acc.x, k);
        acc.y += __shfl_xor(acc.y, k);
        acc.z += __shfl_xor(acc.z, k);
        acc.w += __shfl_xor(acc.w, k);
    }
    __syncthreads();   // tv reads done; reuse buffer head for partials
    float4* CP = (float4*)smem;
    if (g == 0) CP[w * 16 + c] = acc;
    __syncthreads();
    if (tid < 16) {
        float4 s = CP[tid];
        #pragma unroll
        for (int ww = 1; ww < 4; ++ww) {
            const float4 t4 = CP[ww * 16 + tid];
            s.x += t4.x; s.y += t4.y; s.z += t4.z; s.w += t4.w;
        }
        ((float4*)(ctx_tv + (size_t)bi * HID))[tid] = s;
    }
#undef STAGE
}

// ---------------- Kernel 4: ctx_vp[b,h,i,:] = sum_j P[b,h,i,j] * vp_h[b,j,:]
__global__ __launch_bounds__(256) void k_pv(
    const float* __restrict__ P, const float* __restrict__ vp,
    float* __restrict__ ctx_vp)       // [B*NH*N, D]
{
    __shared__ float sV[200][33];
    const int tid = threadIdx.x;
    const int bid = blockIdx.x;
    const int it  = bid & 7;
    const int bh  = bid >> 3;
    const int b   = bh >> 1;
    const int h   = bh & 1;
    const int i0  = it * 25;

    for (int e = tid; e < 200 * 32; e += 256) {
        const int j = e >> 5, d = e & 31;
        sV[j][d] = vp[((size_t)b * N + j) * HID + h * D + d];
    }
    __syncthreads();

    for (int e = tid; e < 25 * 32; e += 256) {
        const int ii = e >> 5, d = e & 31;
        const float* pr = P + ((size_t)bh * N + i0 + ii) * N;
        float acc = 0.0f;
        #pragma unroll 8
        for (int j = 0; j < 200; ++j)
            acc = fmaf(pr[j], sV[j][d], acc);
        ctx_vp[((size_t)bh * N + i0 + ii) * D + d] = acc;
    }
}

// ---------------- Kernel 5: combine + output proj + residual + LayerNorm ---
__global__ __launch_bounds__(256) void k_out(
    const float* __restrict__ ctx_tv, const float* __restrict__ ctx_vp,
    const float* __restrict__ x,
    const float* __restrict__ Wd, const float* __restrict__ bd,
    const float* __restrict__ ln_g, const float* __restrict__ ln_b,
    float* __restrict__ out)
{
    __shared__ float sC[4][HID];
    const int tid = threadIdx.x;
    const int sub = tid >> 6;
    const int o   = tid & 63;
    const int row = blockIdx.x * 4 + sub;
    const int b   = row / N;
    const int i   = row - b * N;
    const int h   = o >> 5;

    sC[sub][o] = ctx_tv[(size_t)row * HID + o]
               + ctx_vp[((size_t)(b * NH + h) * N + i) * D + (o & 31)];
    __syncthreads();

    float hv = bd[o] + x[(size_t)row * HID + o];
    #pragma unroll 8
    for (int c = 0; c < HID; ++c)
        hv = fmaf(sC[sub][c], Wd[o * HID + c], hv);

    float sum = hv;
    #pragma unroll
    for (int m = 32; m >= 1; m >>= 1) sum += __shfl_xor(sum, m);
    const float mu = sum * (1.0f / 64.0f);
    const float dv = hv - mu;
    float vs = dv * dv;
    #pragma unroll
    for (int m = 32; m >= 1; m >>= 1) vs += __shfl_xor(vs, m);
    const float var = vs * (1.0f / 64.0f);

    out[(size_t)row * HID + o] = dv * rsqrtf(var + EPSF) * ln_g[o] + ln_b[o];
}

extern "C" void kernel_launch(void* const* d_in, const int* in_sizes, int n_in,
                              void* d_out, int out_size, void* d_ws, size_t ws_size,
                              hipStream_t stream) {
    const float* x     = (const float*)d_in[0];
    const float* amask = (const float*)d_in[1];
    const float* apk   = (const float*)d_in[2];
    const float* apv   = (const float*)d_in[3];
    const float* tk    = (const float*)d_in[4];
    const float* tv    = (const float*)d_in[5];
    const float* Wq    = (const float*)d_in[6];
    const float* bq    = (const float*)d_in[7];
    const float* Wk    = (const float*)d_in[8];
    const float* bk    = (const float*)d_in[9];
    const float* Wv    = (const float*)d_in[10];
    const float* bv    = (const float*)d_in[11];
    const float* Wd    = (const float*)d_in[12];
    const float* bd    = (const float*)d_in[13];
    const float* order_w = (const float*)d_in[14];
    const float* order_b = (const float*)d_in[15];
    const float* dist_w  = (const float*)d_in[16];
    const float* dist_b  = (const float*)d_in[17];
    const float* scalar  = (const float*)d_in[18];
    const float* ln_g    = (const float*)d_in[19];
    const float* ln_b    = (const float*)d_in[20];

    float* ws = (float*)d_ws;
    const size_t nrow = (size_t)B * N * HID;        // 819200
    const size_t nbh  = (size_t)B * NH * N;         // 6400
    float* qbuf   = ws;
    float* kpbuf  = qbuf  + nrow;
    float* vpbuf  = kpbuf + nrow;
    float* ctxtv  = vpbuf + nrow;
    float* ctxvp  = ctxtv + nrow;                   // nbh*D = 204800
    float* qob    = ctxvp + (size_t)nbh * D;
    float* kob    = qob + nbh;
    float* qdb    = kob + nbh;
    float* kdb    = qdb + nbh;
    float* Spre   = kdb + nbh;                      // nbh*N = 1.28M
    float* Pbuf   = Spre + (size_t)nbh * N;         // nbh*N = 1.28M

    k_proj<<<(B * N) / 4, 256, 0, stream>>>(x, apk, apv, Wq, bq, Wk, bk, Wv, bv,
                                            order_w, dist_w,
                                            qbuf, kpbuf, vpbuf, qob, kob, qdb, kdb);

    k_pre<<<B * NH * 8, 256, 0, stream>>>(qbuf, kpbuf, amask, qob, kob, qdb, kdb,
                                          order_b, dist_b, scalar, Spre);

    k_attn<<<B * N, 256, 0, stream>>>(qbuf, tk, tv, Spre, Pbuf, ctxtv);

    k_pv<<<B * NH * 8, 256, 0, stream>>>(Pbuf, vpbuf, ctxvp);

    k_out<<<(B * N) / 4, 256, 0, stream>>>(ctxtv, ctxvp, x, Wd, bd, ln_g, ln_b,
                                           (float*)d_out);
}

// Round 10
// 144.126 us; speedup vs baseline: 1.0273x; 1.0273x over previous
//
#include <hip/hip_runtime.h>
#include <math.h>

#define B 16
#define N 200
#define HID 64
#define NH 2
#define D 32
#define EPSF 1e-12f

// 1/sqrt(32)
#define RSQRT_D 0.17677669529663687f

// ---------------- Kernel 1: projections + folded pos + order/dist scalars ----
__global__ __launch_bounds__(256) void k_proj(
    const float* __restrict__ x,
    const float* __restrict__ pk,
    const float* __restrict__ pv,
    const float* __restrict__ Wq, const float* __restrict__ bq,
    const float* __restrict__ Wk, const float* __restrict__ bk,
    const float* __restrict__ Wv, const float* __restrict__ bv,
    const float* __restrict__ order_w, const float* __restrict__ dist_w,
    float* __restrict__ q,
    float* __restrict__ kp,
    float* __restrict__ vp,
    float* __restrict__ qo, float* __restrict__ ko,
    float* __restrict__ qd, float* __restrict__ kd)
{
    __shared__ float sX[4][HID];
    const int tid = threadIdx.x;
    const int sub = tid >> 6;
    const int o   = tid & 63;
    const int row = blockIdx.x * 4 + sub;

    sX[sub][o] = x[row * HID + o];
    __syncthreads();

    float qv = bq[o], kv = bk[o], vv = bv[o];
    #pragma unroll 8
    for (int c = 0; c < HID; ++c) {
        const float xv = sX[sub][c];
        qv = fmaf(xv, Wq[o * HID + c], qv);
        kv = fmaf(xv, Wk[o * HID + c], kv);
        vv = fmaf(xv, Wv[o * HID + c], vv);
    }
    q [row * HID + o] = qv;
    kp[row * HID + o] = kv + pk[row * HID + o];
    vp[row * HID + o] = vv + pv[row * HID + o];

    const int d = o & 31;
    float qov = qv * order_w[d];
    float kov = kv * order_w[D + d];
    float qdv = qv * dist_w[d];
    float kdv = kv * dist_w[D + d];
    #pragma unroll
    for (int m = 16; m >= 1; m >>= 1) {
        qov += __shfl_xor(qov, m);
        kov += __shfl_xor(kov, m);
        qdv += __shfl_xor(qdv, m);
        kdv += __shfl_xor(kdv, m);
    }
    if (d == 0) {
        const int bb = row / N;
        const int ii = row - bb * N;
        const int h  = o >> 5;
        const int idx = (bb * NH + h) * N + ii;
        qo[idx] = qov;  ko[idx] = kov;
        qd[idx] = qdv;  kd[idx] = kdv;
    }
}

// ---------------- Kernel 2: S_pre[b,h,i,j] = (q.kp + order + dist)/sqrtD + mask
__global__ __launch_bounds__(256) void k_pre(
    const float* __restrict__ q, const float* __restrict__ kp,
    const float* __restrict__ amask,
    const float* __restrict__ qo, const float* __restrict__ ko,
    const float* __restrict__ qd, const float* __restrict__ kd,
    const float* __restrict__ order_b, const float* __restrict__ dist_b,
    const float* __restrict__ scalar,
    float* __restrict__ S_pre)        // [B*NH*N, N]
{
    __shared__ float sQ[25][33];
    __shared__ float sK[200][33];
    __shared__ float sGd[200];
    __shared__ float sQo[25], sQd[25];
    __shared__ float sKo[200], sKd[200];

    const int tid = threadIdx.x;
    const int bid = blockIdx.x;
    const int it  = bid & 7;          // i-tile
    const int bh  = bid >> 3;
    const int b   = bh >> 1;
    const int h   = bh & 1;
    const int i0  = it * 25;

    for (int e = tid; e < 200 * 32; e += 256) {
        const int j = e >> 5, d = e & 31;
        sK[j][d] = kp[((size_t)b * N + j) * HID + h * D + d];
    }
    for (int e = tid; e < 25 * 32; e += 256) {
        const int ii = e >> 5, d = e & 31;
        sQ[ii][d] = q[((size_t)b * N + i0 + ii) * HID + h * D + d];
    }
    for (int e = tid; e < 200; e += 256) {
        sGd[e] = logf((float)e + 1.0f);
        sKo[e] = ko[(size_t)bh * N + e];
        sKd[e] = kd[(size_t)bh * N + e];
    }
    if (tid < 25) {
        sQo[tid] = qo[(size_t)bh * N + i0 + tid];
        sQd[tid] = qd[(size_t)bh * N + i0 + tid];
    }
    const float ob = order_b[0];
    const float db = dist_b[0];
    const float sc = scalar[0];
    const float sc2h = 0.5f * sc * sc;
    __syncthreads();

    for (int e = tid; e < 25 * 200; e += 256) {
        const int ii = e / 200;
        const int jj = e - ii * 200;
        const int i  = i0 + ii;
        float dot = 0.0f;
        #pragma unroll
        for (int d = 0; d < 32; ++d)
            dot = fmaf(sQ[ii][d], sK[jj][d], dot);
        const float lo = sQo[ii] + sKo[jj] + ob;
        const float xs = (jj > i) ? -lo : lo;
        const float eo = -log1pf(expf(xs));
        const float pd = sQd[ii] + sKd[jj] + db;
        const int   ad = (jj > i) ? (jj - i) : (i - jj);
        const float dv = sGd[ad] - pd;
        const float ed = -sc2h * dv * dv;
        S_pre[((size_t)bh * N + i) * N + jj] =
            (dot + eo + ed) * RSQRT_D + amask[((size_t)b * N + i) * N + jj];
    }
}

// ---------------- Kernel 3: stream tk/tv h-slices; softmax; P; ctx_tv -------
// R3's proven shape: grid = B*NH*N one-wave blocks (6400 waves, ~59% occ),
// zero barriers, lane = 8*g + c. Per-block bytes cut 103KB -> 53KB via
// S_pre (k_pre) and PV offload (k_pv): streams ONLY tk + tv h-slices.
__global__ __launch_bounds__(64) void k_attn(
    const float* __restrict__ q,
    const float* __restrict__ tk,     // [B,N,N,HID]
    const float* __restrict__ tv,
    const float* __restrict__ S_pre,  // [B*NH*N, N]
    float* __restrict__ P,            // [B*NH*N, N]
    float* __restrict__ ctx_tv)       // [B*N, HID]
{
    __shared__ float S_dot[200];
    __shared__ float SP[200];

    const int lane = threadIdx.x;
    const int g    = lane >> 3;       // j subgroup 0..7
    const int c    = lane & 7;        // float4 column 0..7
    const int bid  = blockIdx.x;      // bh*N + i
    const int bh   = bid / N;
    const int i    = bid - bh * N;
    const int b    = bh >> 1;
    const int h    = bh & 1;
    const int bi   = b * N + i;

    float4 qf = ((const float4*)(q + (size_t)bi * HID + h * D))[c];
    qf.x *= RSQRT_D; qf.y *= RSQRT_D; qf.z *= RSQRT_D; qf.w *= RSQRT_D;

    const float4* tkR = (const float4*)(tk + (size_t)bi * N * HID + h * D);
    const float4* tvR = (const float4*)(tv + (size_t)bi * N * HID + h * D);
    const float*  spr = S_pre + ((size_t)bh * N + i) * N;

    // S_pre row into registers (coalesced, issued early)
    const float sp0 = spr[lane];
    const float sp1 = spr[lane + 64];
    const float sp2 = spr[lane + 128];
    const float sp3 = (lane < 8) ? spr[lane + 192] : 0.0f;

    // ---- phase B: streaming tk dots ----
    #pragma unroll 5
    for (int it = 0; it < 25; ++it) {
        const int j = it * 8 + g;
        const float4 f = tkR[j * 16 + c];
        float part = qf.x * f.x + qf.y * f.y + qf.z * f.z + qf.w * f.w;
        part += __shfl_xor(part, 1);
        part += __shfl_xor(part, 2);
        part += __shfl_xor(part, 4);
        if (c == 0) S_dot[j] = part;
    }
    asm volatile("s_waitcnt lgkmcnt(0)" ::: "memory");

    // ---- softmax over 200 ----
    const float s0 = sp0 + S_dot[lane];
    const float s1 = sp1 + S_dot[lane + 64];
    const float s2 = sp2 + S_dot[lane + 128];
    const float s3 = (lane < 8) ? (sp3 + S_dot[lane + 192]) : -INFINITY;
    float m = fmaxf(fmaxf(s0, s1), fmaxf(s2, s3));
    #pragma unroll
    for (int k = 32; k >= 1; k >>= 1) m = fmaxf(m, __shfl_xor(m, k));
    const float e0 = expf(s0 - m);
    const float e1 = expf(s1 - m);
    const float e2 = expf(s2 - m);
    const float e3 = (lane < 8) ? expf(s3 - m) : 0.0f;
    float t = e0 + e1 + e2 + e3;
    #pragma unroll
    for (int k = 32; k >= 1; k >>= 1) t += __shfl_xor(t, k);
    const float rinv = 1.0f / t;
    const float p0 = e0 * rinv, p1 = e1 * rinv, p2 = e2 * rinv, p3 = e3 * rinv;
    SP[lane]       = p0;
    SP[lane + 64]  = p1;
    SP[lane + 128] = p2;
    if (lane < 8) SP[lane + 192] = p3;

    // publish P for k_pv (coalesced row)
    float* prow = P + ((size_t)bh * N + i) * N;
    prow[lane]       = p0;
    prow[lane + 64]  = p1;
    prow[lane + 128] = p2;
    if (lane < 8) prow[lane + 192] = p3;

    asm volatile("s_waitcnt lgkmcnt(0)" ::: "memory");

    // ---- phase C: ctx_tv = sum_j p_j * tv[i,j] (h-slice) ----
    float4 acc = make_float4(0.f, 0.f, 0.f, 0.f);
    #pragma unroll 5
    for (int it = 0; it < 25; ++it) {
        const int j = it * 8 + g;
        const float pj = SP[j];
        const float4 f = tvR[j * 16 + c];
        acc.x = fmaf(pj, f.x, acc.x);
        acc.y = fmaf(pj, f.y, acc.y);
        acc.z = fmaf(pj, f.z, acc.z);
        acc.w = fmaf(pj, f.w, acc.w);
    }
    // reduce across the 8 j-subgroups (lanes sharing c): masks 8,16,32
    #pragma unroll
    for (int k = 8; k <= 32; k <<= 1) {
        acc.x += __shfl_xor(acc.x, k);
        acc.y += __shfl_xor(acc.y, k);
        acc.z += __shfl_xor(acc.z, k);
        acc.w += __shfl_xor(acc.w, k);
    }
    if (g == 0)
        ((float4*)(ctx_tv + (size_t)bi * HID + h * D))[c] = acc;
}

// ---------------- Kernel 4: ctx_vp[b,h,i,:] = sum_j P[b,h,i,j] * vp_h[b,j,:]
__global__ __launch_bounds__(256) void k_pv(
    const float* __restrict__ P, const float* __restrict__ vp,
    float* __restrict__ ctx_vp)       // [B*NH*N, D]
{
    __shared__ float sV[200][33];
    const int tid = threadIdx.x;
    const int bid = blockIdx.x;
    const int it  = bid & 7;
    const int bh  = bid >> 3;
    const int b   = bh >> 1;
    const int h   = bh & 1;
    const int i0  = it * 25;

    for (int e = tid; e < 200 * 32; e += 256) {
        const int j = e >> 5, d = e & 31;
        sV[j][d] = vp[((size_t)b * N + j) * HID + h * D + d];
    }
    __syncthreads();

    for (int e = tid; e < 25 * 32; e += 256) {
        const int ii = e >> 5, d = e & 31;
        const float* pr = P + ((size_t)bh * N + i0 + ii) * N;
        float acc = 0.0f;
        #pragma unroll 8
        for (int j = 0; j < 200; ++j)
            acc = fmaf(pr[j], sV[j][d], acc);
        ctx_vp[((size_t)bh * N + i0 + ii) * D + d] = acc;
    }
}

// ---------------- Kernel 5: combine + output proj + residual + LayerNorm ---
__global__ __launch_bounds__(256) void k_out(
    const float* __restrict__ ctx_tv, const float* __restrict__ ctx_vp,
    const float* __restrict__ x,
    const float* __restrict__ Wd, const float* __restrict__ bd,
    const float* __restrict__ ln_g, const float* __restrict__ ln_b,
    float* __restrict__ out)
{
    __shared__ float sC[4][HID];
    const int tid = threadIdx.x;
    const int sub = tid >> 6;
    const int o   = tid & 63;
    const int row = blockIdx.x * 4 + sub;
    const int b   = row / N;
    const int i   = row - b * N;
    const int h   = o >> 5;

    sC[sub][o] = ctx_tv[(size_t)row * HID + o]
               + ctx_vp[((size_t)(b * NH + h) * N + i) * D + (o & 31)];
    __syncthreads();

    float hv = bd[o] + x[(size_t)row * HID + o];
    #pragma unroll 8
    for (int c = 0; c < HID; ++c)
        hv = fmaf(sC[sub][c], Wd[o * HID + c], hv);

    float sum = hv;
    #pragma unroll
    for (int m = 32; m >= 1; m >>= 1) sum += __shfl_xor(sum, m);
    const float mu = sum * (1.0f / 64.0f);
    const float dv = hv - mu;
    float vs = dv * dv;
    #pragma unroll
    for (int m = 32; m >= 1; m >>= 1) vs += __shfl_xor(vs, m);
    const float var = vs * (1.0f / 64.0f);

    out[(size_t)row * HID + o] = dv * rsqrtf(var + EPSF) * ln_g[o] + ln_b[o];
}

extern "C" void kernel_launch(void* const* d_in, const int* in_sizes, int n_in,
                              void* d_out, int out_size, void* d_ws, size_t ws_size,
                              hipStream_t stream) {
    const float* x     = (const float*)d_in[0];
    const float* amask = (const float*)d_in[1];
    const float* apk   = (const float*)d_in[2];
    const float* apv   = (const float*)d_in[3];
    const float* tk    = (const float*)d_in[4];
    const float* tv    = (const float*)d_in[5];
    const float* Wq    = (const float*)d_in[6];
    const float* bq    = (const float*)d_in[7];
    const float* Wk    = (const float*)d_in[8];
    const float* bk    = (const float*)d_in[9];
    const float* Wv    = (const float*)d_in[10];
    const float* bv    = (const float*)d_in[11];
    const float* Wd    = (const float*)d_in[12];
    const float* bd    = (const float*)d_in[13];
    const float* order_w = (const float*)d_in[14];
    const float* order_b = (const float*)d_in[15];
    const float* dist_w  = (const float*)d_in[16];
    const float* dist_b  = (const float*)d_in[17];
    const float* scalar  = (const float*)d_in[18];
    const float* ln_g    = (const float*)d_in[19];
    const float* ln_b    = (const float*)d_in[20];

    float* ws = (float*)d_ws;
    const size_t nrow = (size_t)B * N * HID;        // 819200
    const size_t nbh  = (size_t)B * NH * N;         // 6400
    float* qbuf   = ws;
    float* kpbuf  = qbuf  + nrow;
    float* vpbuf  = kpbuf + nrow;
    float* ctxtv  = vpbuf + nrow;
    float* ctxvp  = ctxtv + nrow;                   // nbh*D = 204800
    float* qob    = ctxvp + (size_t)nbh * D;
    float* kob    = qob + nbh;
    float* qdb    = kob + nbh;
    float* kdb    = qdb + nbh;
    float* Spre   = kdb + nbh;                      // nbh*N = 1.28M
    float* Pbuf   = Spre + (size_t)nbh * N;         // nbh*N = 1.28M

    k_proj<<<(B * N) / 4, 256, 0, stream>>>(x, apk, apv, Wq, bq, Wk, bk, Wv, bv,
                                            order_w, dist_w,
                                            qbuf, kpbuf, vpbuf, qob, kob, qdb, kdb);

    k_pre<<<B * NH * 8, 256, 0, stream>>>(qbuf, kpbuf, amask, qob, kob, qdb, kdb,
                                          order_b, dist_b, scalar, Spre);

    k_attn<<<B * NH * N, 64, 0, stream>>>(qbuf, tk, tv, Spre, Pbuf, ctxtv);

    k_pv<<<B * NH * 8, 256, 0, stream>>>(Pbuf, vpbuf, ctxvp);

    k_out<<<(B * N) / 4, 256, 0, stream>>>(ctxtv, ctxvp, x, Wd, bd, ln_g, ln_b,
                                           (float*)d_out);
}

// Round 11
// 106.437 us; speedup vs baseline: 1.3910x; 1.3541x over previous
//
#include <hip/hip_runtime.h>
#include <math.h>

#define B 16
#define N 200
#define HID 64
#define NH 2
#define D 32
#define EPSF 1e-12f
#define LOG_EPSF 1e-24f

// 1/sqrt(32)
#define RSQRT_D 0.17677669529663687f

// ---------------- Kernel 1: projections + folded pos + order/dist scalars ----
// grid = B*N/4 blocks, 256 threads (4 rows per block, one wave per row)
__global__ __launch_bounds__(256) void k_proj(
    const float* __restrict__ x,       // [B*N, HID]
    const float* __restrict__ pk,      // absolute_pos_K [B*N, HID]
    const float* __restrict__ pv,      // absolute_pos_V
    const float* __restrict__ Wq, const float* __restrict__ bq,
    const float* __restrict__ Wk, const float* __restrict__ bk,
    const float* __restrict__ Wv, const float* __restrict__ bv,
    const float* __restrict__ order_w, const float* __restrict__ dist_w,
    float* __restrict__ q,             // [B*N, HID]
    float* __restrict__ kp,            // k + pk
    float* __restrict__ vp,            // v + pv
    float* __restrict__ qo, float* __restrict__ ko,   // [B*NH*N]
    float* __restrict__ qd, float* __restrict__ kd)
{
    __shared__ float sX[4][HID];
    const int tid = threadIdx.x;
    const int sub = tid >> 6;      // row within block
    const int o   = tid & 63;      // output channel (== lane)
    const int row = blockIdx.x * 4 + sub;        // [0, B*N)

    sX[sub][o] = x[row * HID + o];
    __syncthreads();

    float qv = bq[o], kv = bk[o], vv = bv[o];
    #pragma unroll 8
    for (int c = 0; c < HID; ++c) {
        const float xv = sX[sub][c];
        qv = fmaf(xv, Wq[o * HID + c], qv);
        kv = fmaf(xv, Wk[o * HID + c], kv);
        vv = fmaf(xv, Wv[o * HID + c], vv);
    }
    q [row * HID + o] = qv;
    kp[row * HID + o] = kv + pk[row * HID + o];
    vp[row * HID + o] = vv + pv[row * HID + o];

    // order / dist rank-1 scalars; lanes 0..31 = head 0, lanes 32..63 = head 1
    const int d = o & 31;
    float qov = qv * order_w[d];
    float kov = kv * order_w[D + d];
    float qdv = qv * dist_w[d];
    float kdv = kv * dist_w[D + d];
    #pragma unroll
    for (int m = 16; m >= 1; m >>= 1) {
        qov += __shfl_xor(qov, m);   // stays within 32-lane half for m<=16
        kov += __shfl_xor(kov, m);
        qdv += __shfl_xor(qdv, m);
        kdv += __shfl_xor(kdv, m);
    }
    if (d == 0) {
        const int bb = row / N;
        const int ii = row - bb * N;
        const int h  = o >> 5;
        const int idx = (bb * NH + h) * N + ii;
        qo[idx] = qov;  ko[idx] = kov;
        qd[idx] = qdv;  kd[idx] = kdv;
    }
}

// ---------------- Kernel 2: fused scores + softmax + context --------------
// grid = B*NH*N blocks, 64 threads = ONE WAVE per (b,h,i). Zero barriers.
// This is the best-measured configuration (R3, 106.9 us total): the kp/vp
// re-reads are L2-hits riding free under the compulsory tk/tv L3-stream
// (~3.1 TB/s platform ceiling for read-streaming), and the aux
// transcendentals are hoisted into phase A where they overlap the stream.
__global__ __launch_bounds__(64) void k_attn(
    const float* __restrict__ q, const float* __restrict__ kp,
    const float* __restrict__ vp,
    const float* __restrict__ tk,     // [B,N,N,HID]
    const float* __restrict__ tv,
    const float* __restrict__ amask,  // [B,1,N,N]
    const float* __restrict__ qo, const float* __restrict__ ko,
    const float* __restrict__ qd, const float* __restrict__ kd,
    const float* __restrict__ order_b, const float* __restrict__ dist_b,
    const float* __restrict__ scalar,
    float* __restrict__ ctx)          // [B*N, HID]
{
    __shared__ float S_aux[256];
    __shared__ float S_dot[256];

    const int lane = threadIdx.x;
    const int g    = lane >> 3;       // j subgroup 0..7
    const int c    = lane & 7;        // float4 column 0..7
    const int bid  = blockIdx.x;      // bh*N + i
    const int bh   = bid / N;
    const int i    = bid - bh * N;
    const int b    = bh >> 1;         // NH == 2
    const int h    = bh & 1;
    const int bi   = b * N + i;

    // per-lane q fragment (4 dims)
    const float4 qf = ((const float4*)(q + (size_t)bi * HID + h * D))[c];

    // wave-uniform scalars
    const float qoi = qo[bh * N + i];
    const float qdi = qd[bh * N + i];
    const float ob  = order_b[0];
    const float db  = dist_b[0];
    const float sc  = scalar[0];
    const float sc2h = 0.5f * sc * sc;

    const float* kpb = kp + (size_t)b * N * HID + h * D;          // + j*HID
    const float* tkb = tk + (size_t)bi * N * HID + h * D;         // + j*HID
    const float* vpb = vp + (size_t)b * N * HID + h * D;
    const float* tvb = tv + (size_t)bi * N * HID + h * D;
    const float* mb  = amask + (size_t)bi * N;                    // + j
    const float* kob = ko + (size_t)bh * N;
    const float* kdb = kd + (size_t)bh * N;

    // ---- phase A: additive aux term per j (transcendentals, once per j) ----
    #pragma unroll
    for (int r = 0; r < 4; ++r) {
        const int j = r * 64 + lane;
        if (j < N) {
            const float lo = qoi + kob[j] + ob;
            // j>i: log(sigmoid(lo)) = -log1p(exp(-lo)); else log(1-sigmoid(lo))
            const float xs = (j > i) ? -lo : lo;
            const float eo = -log1pf(expf(xs));
            const float pd = qdi + kdb[j] + db;
            const float gd = logf((float)(j > i ? j - i : i - j) + 1.0f);
            const float dv = gd - pd;
            S_aux[j] = (eo - sc2h * dv * dv) * RSQRT_D + mb[j];
        }
    }

    // ---- phase B: pure streaming dot products ----
    #pragma unroll 5
    for (int it = 0; it < 25; ++it) {
        const int j = it * 8 + g;
        const float4 kv  = ((const float4*)(kpb + (size_t)j * HID))[c];
        const float4 tkv = ((const float4*)(tkb + (size_t)j * HID))[c];
        float part = qf.x * (kv.x + tkv.x) + qf.y * (kv.y + tkv.y)
                   + qf.z * (kv.z + tkv.z) + qf.w * (kv.w + tkv.w);
        part += __shfl_xor(part, 1);
        part += __shfl_xor(part, 2);
        part += __shfl_xor(part, 4);
        if (c == 0) S_dot[j] = part * RSQRT_D;
    }
    asm volatile("s_waitcnt lgkmcnt(0)" ::: "memory");

    // ---- softmax over 200 (within wave, shuffle reductions) ----
    const float s0 = S_aux[lane]       + S_dot[lane];
    const float s1 = S_aux[lane + 64]  + S_dot[lane + 64];
    const float s2 = S_aux[lane + 128] + S_dot[lane + 128];
    const float s3 = (lane < 8) ? (S_aux[lane + 192] + S_dot[lane + 192]) : -INFINITY;
    float m = fmaxf(fmaxf(s0, s1), fmaxf(s2, s3));
    #pragma unroll
    for (int k = 32; k >= 1; k >>= 1) m = fmaxf(m, __shfl_xor(m, k));
    const float e0 = expf(s0 - m);
    const float e1 = expf(s1 - m);
    const float e2 = expf(s2 - m);
    const float e3 = (lane < 8) ? expf(s3 - m) : 0.0f;
    float t = e0 + e1 + e2 + e3;
    #pragma unroll
    for (int k = 32; k >= 1; k >>= 1) t += __shfl_xor(t, k);
    const float rinv = 1.0f / t;
    S_aux[lane]       = e0 * rinv;
    S_aux[lane + 64]  = e1 * rinv;
    S_aux[lane + 128] = e2 * rinv;
    if (lane < 8) S_aux[lane + 192] = e3 * rinv;
    asm volatile("s_waitcnt lgkmcnt(0)" ::: "memory");

    // ---- phase C: ctx = sum_j p_j * (vp[j] + tv[i,j]) ----
    float4 r4 = make_float4(0.f, 0.f, 0.f, 0.f);
    #pragma unroll 5
    for (int it = 0; it < 25; ++it) {
        const int j = it * 8 + g;
        const float p = S_aux[j];
        const float4 vv  = ((const float4*)(vpb + (size_t)j * HID))[c];
        const float4 tvv = ((const float4*)(tvb + (size_t)j * HID))[c];
        r4.x += p * (vv.x + tvv.x);
        r4.y += p * (vv.y + tvv.y);
        r4.z += p * (vv.z + tvv.z);
        r4.w += p * (vv.w + tvv.w);
    }
    // reduce across the 8 j-subgroups (lanes sharing c): masks 8,16,32
    #pragma unroll
    for (int k = 8; k <= 32; k <<= 1) {
        r4.x += __shfl_xor(r4.x, k);
        r4.y += __shfl_xor(r4.y, k);
        r4.z += __shfl_xor(r4.z, k);
        r4.w += __shfl_xor(r4.w, k);
    }
    if (g == 0)
        ((float4*)(ctx + (size_t)bi * HID + h * D))[c] = r4;
}

// ---------------- Kernel 3: output proj + residual + LayerNorm ------------
__global__ __launch_bounds__(256) void k_out(
    const float* __restrict__ ctx, const float* __restrict__ x,
    const float* __restrict__ Wd, const float* __restrict__ bd,
    const float* __restrict__ ln_g, const float* __restrict__ ln_b,
    float* __restrict__ out)
{
    __shared__ float sC[4][HID];
    const int tid = threadIdx.x;
    const int sub = tid >> 6;
    const int o   = tid & 63;
    const int row = blockIdx.x * 4 + sub;

    sC[sub][o] = ctx[row * HID + o];
    __syncthreads();

    float hv = bd[o] + x[row * HID + o];
    #pragma unroll 8
    for (int c = 0; c < HID; ++c)
        hv = fmaf(sC[sub][c], Wd[o * HID + c], hv);

    float sum = hv;
    #pragma unroll
    for (int m = 32; m >= 1; m >>= 1) sum += __shfl_xor(sum, m);
    const float mu = sum * (1.0f / 64.0f);
    const float dv = hv - mu;
    float vs = dv * dv;
    #pragma unroll
    for (int m = 32; m >= 1; m >>= 1) vs += __shfl_xor(vs, m);
    const float var = vs * (1.0f / 64.0f);

    out[row * HID + o] = dv * rsqrtf(var + EPSF) * ln_g[o] + ln_b[o];
}

extern "C" void kernel_launch(void* const* d_in, const int* in_sizes, int n_in,
                              void* d_out, int out_size, void* d_ws, size_t ws_size,
                              hipStream_t stream) {
    const float* x     = (const float*)d_in[0];
    const float* amask = (const float*)d_in[1];
    const float* apk   = (const float*)d_in[2];
    const float* apv   = (const float*)d_in[3];
    const float* tk    = (const float*)d_in[4];
    const float* tv    = (const float*)d_in[5];
    const float* Wq    = (const float*)d_in[6];
    const float* bq    = (const float*)d_in[7];
    const float* Wk    = (const float*)d_in[8];
    const float* bk    = (const float*)d_in[9];
    const float* Wv    = (const float*)d_in[10];
    const float* bv    = (const float*)d_in[11];
    const float* Wd    = (const float*)d_in[12];
    const float* bd    = (const float*)d_in[13];
    const float* order_w = (const float*)d_in[14];
    const float* order_b = (const float*)d_in[15];
    const float* dist_w  = (const float*)d_in[16];
    const float* dist_b  = (const float*)d_in[17];
    const float* scalar  = (const float*)d_in[18];
    const float* ln_g    = (const float*)d_in[19];
    const float* ln_b    = (const float*)d_in[20];

    float* ws = (float*)d_ws;
    const size_t nrow = (size_t)B * N * HID;       // 819200
    float* qbuf  = ws;
    float* kpbuf = ws + nrow;
    float* vpbuf = ws + 2 * nrow;
    float* ctxb  = ws + 3 * nrow;
    float* qob   = ws + 4 * nrow;
    float* kob   = qob + (size_t)B * NH * N;
    float* qdb   = kob + (size_t)B * NH * N;
    float* kdb   = qdb + (size_t)B * NH * N;

    k_proj<<<(B * N) / 4, 256, 0, stream>>>(x, apk, apv, Wq, bq, Wk, bk, Wv, bv,
                                            order_w, dist_w,
                                            qbuf, kpbuf, vpbuf, qob, kob, qdb, kdb);

    k_attn<<<B * NH * N, 64, 0, stream>>>(qbuf, kpbuf, vpbuf, tk, tv, amask,
                                          qob, kob, qdb, kdb,
                                          order_b, dist_b, scalar, ctxb);

    k_out<<<(B * N) / 4, 256, 0, stream>>>(ctxb, x, Wd, bd, ln_g, ln_b,
                                           (float*)d_out);
}